// Round 12
// baseline (206.214 us; speedup 1.0000x reference)
//
#include <hip/hip_runtime.h>
#include <hip/hip_bf16.h>
#include <cstdint>
#include <cstddef>

typedef __bf16 bf16;
typedef __bf16 bf16x8 __attribute__((ext_vector_type(8)));
typedef float f32x4 __attribute__((ext_vector_type(4)));
typedef unsigned int u32x4 __attribute__((ext_vector_type(4)));
typedef unsigned int u32x2 __attribute__((ext_vector_type(2)));

#define DEVINL __device__ __forceinline__

namespace {
constexpr int Bb = 4, Ss = 2048, Ee = 1024, Hh = 16;
constexpr int Mm = Bb * Ss;      // 8192 rows
constexpr int N_QKV = 3 * Ee;    // 3072
constexpr float SCQ = 0.03125f * 1.44269504f;  // (1/sqrt(E)) * log2(e), folded into Q
}

DEVINL void gl_lds16(const bf16* g, bf16* l) {
  __builtin_amdgcn_global_load_lds((const __attribute__((address_space(1))) void*)g,
                                   (__attribute__((address_space(3))) void*)l, 16, 0, 0);
}

DEVINL unsigned int pkbf(float a, float b) {
  bf16 x = (bf16)a, y = (bf16)b;
  return (unsigned int)__builtin_bit_cast(unsigned short, x) |
         ((unsigned int)__builtin_bit_cast(unsigned short, y) << 16);
}

// ---------------- converters ----------------

__global__ void k_cvt_bf16(const float* __restrict__ in, bf16* __restrict__ out, int n) {
  int i = (blockIdx.x * 256 + threadIdx.x) * 8;
  if (i >= n) return;
  float4 a = *(const float4*)(in + i);
  float4 c = *(const float4*)(in + i + 4);
  bf16x8 v = {(bf16)a.x, (bf16)a.y, (bf16)a.z, (bf16)a.w,
              (bf16)c.x, (bf16)c.y, (bf16)c.z, (bf16)c.w};
  *(bf16x8*)(out + i) = v;
}

// out[c][r] = (bf16) in[r][c];  in: R x C f32 row-major. block (32,8), grid (C/32, R/32)
__global__ void k_transpose_cvt(const float* __restrict__ in, bf16* __restrict__ out, int R, int C) {
  __shared__ float tile[32][33];
  const int c0 = blockIdx.x * 32, r0 = blockIdx.y * 32;
  const int tx = threadIdx.x, ty = threadIdx.y;
  for (int i = 0; i < 32; i += 8)
    tile[ty + i][tx] = in[(size_t)(r0 + ty + i) * C + (c0 + tx)];
  __syncthreads();
  for (int i = 0; i < 32; i += 8)
    out[(size_t)(c0 + ty + i) * R + (r0 + tx)] = (bf16)tile[tx][ty + i];
}

// ------------- 3-buffer deep-pipelined GEMM core (BM=256, BN=128, BK=64, 512 thr) -------------
// 3-buffer rotation: stage target (t+2)%3 never aliases read buffer t%3, so ONE barrier
// per K-tile and the ds_read_b128 fragment loads overlap the MFMA burst (compiler inserts
// fine-grained lgkmcnt). Counted vmcnt(6) = one full tile's loads left in flight (T4).

DEVINL void gemm_core3(const bf16* __restrict__ A, const bf16* __restrict__ Bt,
                       int m0, int n0, bf16* As, bf16* Bs, f32x4 (&acc)[8][2]) {
  constexpr int K = 1024;
  constexpr int TILEA = 16384;  // 256*64 elems
  constexpr int TILEB = 8192;   // 128*64 elems
  const int tid = threadIdx.x;
  const int w = tid >> 6, lane = tid & 63;
  const int wm = w >> 2, wn = w & 3;
  const int fr = lane & 15, kg = lane >> 4;
  const int gc = (tid & 7) ^ ((tid >> 3) & 7);  // pre-swizzled global chunk
  const int srow = tid >> 3;                    // staging row within 64-row slab
  const bf16* Ag = A + (size_t)(m0 + srow) * K + gc * 8;
  const bf16* Bg = Bt + (size_t)(n0 + srow) * K + gc * 8;
  bf16* AdW = As + w * 512;  // wave-uniform LDS base (w*8 rows * 64)
  bf16* BdW = Bs + w * 512;

#define STAGE_TILE(kt, buf)                                                       \
  {                                                                               \
    for (int i = 0; i < 4; ++i)                                                   \
      gl_lds16(Ag + (kt) + (size_t)(i * 64) * K, AdW + (buf) * TILEA + i * 4096); \
    for (int i = 0; i < 2; ++i)                                                   \
      gl_lds16(Bg + (kt) + (size_t)(i * 64) * K, BdW + (buf) * TILEB + i * 4096); \
  }

  STAGE_TILE(0, 0)
  STAGE_TILE(64, 1)
  constexpr int nt = K / 64;  // 16
  int cur = 0, sb = 2;        // read buffer t%3, stage buffer (t+2)%3
#pragma unroll 1
  for (int t = 0; t < nt; ++t) {
    // drain own-wave loads of tile t (leave tile t+1's 6 in flight); lgkm(0) closes the
    // pre-barrier ds_read window so staging after the barrier can't race pending reads.
    if (t != nt - 1) {
      asm volatile("s_waitcnt vmcnt(6) lgkmcnt(0)" ::: "memory");
    } else {
      asm volatile("s_waitcnt vmcnt(0) lgkmcnt(0)" ::: "memory");
    }
    __builtin_amdgcn_sched_barrier(0);
    __builtin_amdgcn_s_barrier();
    __builtin_amdgcn_sched_barrier(0);
    if (t + 2 < nt) STAGE_TILE((t + 2) * 64, sb)
    __builtin_amdgcn_sched_barrier(0);
    // fragment reads from buf[cur] — NOT fenced from the MFMAs below; compiler overlaps.
    bf16x8 af[2][8], bfx[2][2];
    const bf16* Ab = As + cur * TILEA;
    const bf16* Bb = Bs + cur * TILEB;
    for (int kk = 0; kk < 2; ++kk) {
      const int sw = ((kk * 4 + kg) ^ (fr & 7)) * 8;
      for (int mi = 0; mi < 8; ++mi)
        af[kk][mi] = *(const bf16x8*)(Ab + (wm * 128 + mi * 16 + fr) * 64 + sw);
      for (int ni = 0; ni < 2; ++ni)
        bfx[kk][ni] = *(const bf16x8*)(Bb + (wn * 32 + ni * 16 + fr) * 64 + sw);
    }
    __builtin_amdgcn_s_setprio(1);
    for (int kk = 0; kk < 2; ++kk)
      for (int mi = 0; mi < 8; ++mi)
        for (int ni = 0; ni < 2; ++ni)
          acc[mi][ni] =
              __builtin_amdgcn_mfma_f32_16x16x32_bf16(af[kk][mi], bfx[kk][ni], acc[mi][ni], 0, 0, 0);
    __builtin_amdgcn_s_setprio(0);
    cur = (cur == 2) ? 0 : cur + 1;
    sb = (sb == 2) ? 0 : sb + 1;
  }
#undef STAGE_TILE
}

// QKV GEMM: BN=128. grid (3072/128=24, 8192/256=32) = 768 blocks, 512 threads, 144 KB LDS.
__global__ __launch_bounds__(512, 2) void k_qkv_gemm(const bf16* __restrict__ A,
                                                     const bf16* __restrict__ Bt,
                                                     const float* __restrict__ bias,
                                                     bf16* __restrict__ qbuf,
                                                     bf16* __restrict__ kbuf,
                                                     bf16* __restrict__ vtb) {
  __shared__ bf16 As[3 * 16384];
  __shared__ bf16 Bs[3 * 8192];
  const int m0 = blockIdx.y * 256, n0 = blockIdx.x * 128;
  f32x4 acc[8][2] = {};
  gemm_core3(A, Bt, m0, n0, As, Bs, acc);

  const int tid = threadIdx.x, w = tid >> 6, lane = tid & 63;
  const int wm = w >> 2, wn = w & 3;
  const int fr = lane & 15, kg = lane >> 4;
  const int row_b = m0 >> 11;  // batch index (256-row tile never straddles a batch)
  for (int ni = 0; ni < 2; ++ni) {
    const int col0 = n0 + wn * 32 + ni * 16;  // 16-aligned => never straddles 64-col class
    const int h = col0 / 192;
    const int w192 = col0 - h * 192;
    const int cls = w192 >> 6;  // 0=Q, 1=K, 2=V (wave-uniform per (wn,ni))
    const float bv = bias[col0 + fr];
    if (cls == 2) {
      const int d = w192 - 128 + fr;
      bf16* dstb = vtb + (((size_t)row_b * Hh + h) * 64 + d) * Ss;
      for (int mi = 0; mi < 8; ++mi) {
        const int s0 = (m0 & 2047) + wm * 128 + mi * 16 + kg * 4;
        u32x2 pk2 = {pkbf(acc[mi][ni][0] + bv, acc[mi][ni][1] + bv),
                     pkbf(acc[mi][ni][2] + bv, acc[mi][ni][3] + bv)};
        *(u32x2*)(dstb + s0) = pk2;
      }
    } else {
      bf16* buf = (cls == 0) ? qbuf : kbuf;
      const float sc = (cls == 0) ? SCQ : 1.f;
      const int d = (w192 & 63) + fr;
      bf16* dstb = buf + ((size_t)row_b * Hh + h) * Ss * 64 + d;
      for (int mi = 0; mi < 8; ++mi) {
        const int s0 = (m0 & 2047) + wm * 128 + mi * 16 + kg * 4;
        for (int r = 0; r < 4; ++r)
          dstb[(size_t)(s0 + r) * 64] = (bf16)((acc[mi][ni][r] + bv) * sc);
      }
    }
  }
}

// OUT GEMM: BN=128. grid (8, 32) = 256 blocks, 512 threads, 144 KB LDS.
__global__ __launch_bounds__(512, 2) void k_out_gemm(const bf16* __restrict__ A,
                                                     const bf16* __restrict__ Bt,
                                                     const float* __restrict__ bias,
                                                     float* __restrict__ out) {
  __shared__ bf16 As[3 * 16384];
  __shared__ bf16 Bs[3 * 8192];
  const int m0 = blockIdx.y * 256, n0 = blockIdx.x * 128;
  f32x4 acc[8][2] = {};
  gemm_core3(A, Bt, m0, n0, As, Bs, acc);

  const int tid = threadIdx.x, w = tid >> 6, lane = tid & 63;
  const int wm = w >> 2, wn = w & 3;
  const int fr = lane & 15, kg = lane >> 4;
  for (int ni = 0; ni < 2; ++ni) {
    const int col = n0 + wn * 32 + ni * 16 + fr;
    const float bv = bias[col];
    for (int mi = 0; mi < 8; ++mi) {
      const int mb = m0 + wm * 128 + mi * 16 + kg * 4;
      for (int r = 0; r < 4; ++r)
        out[(size_t)(mb + r) * Ee + col] = acc[mi][ni][r] + bv;
    }
  }
}

// ---------------- flash attention (causal; Q pre-scaled by 1/32*log2e) ----------------
// REVERTED to the r9/r10 source (96 us, measured twice). r11's balanced-qt map +
// deferred-l + tree-max was a 3.5% regression (packing isn't modular round-robin).

__global__ __launch_bounds__(256, 3) void k_attn(const bf16* __restrict__ qbuf,
                                                 const bf16* __restrict__ kbuf,
                                                 const bf16* __restrict__ vtb,
                                                 bf16* __restrict__ vals) {
  const int g = blockIdx.x;
  const int qt = 15 - (g >> 6);   // heavy blocks first (LPT)
  const int bh = g & 63;
  const int b = bh >> 4, h = bh & 15;
  const int q0 = qt * 128;
  const int tid = threadIdx.x, w = tid >> 6, lane = tid & 63;
  const int fr = lane & 15, kg = lane >> 4;
  const int rl = lane >> 3, cl = (lane & 7) ^ (lane >> 3);

  __shared__ bf16 KsB[2][4096];   // [key 64][chunk-swizzled d 64]
  __shared__ bf16 VtB[2][4096];   // [d 64][chunk-swizzled s 64]

  const bf16* qb = qbuf + (size_t)bh * Ss * 64;
  const bf16* kb = kbuf + (size_t)bh * Ss * 64 + (size_t)rl * 64 + cl * 8;
  const bf16* vb = vtb + (size_t)bh * 64 * Ss + (size_t)rl * Ss + cl * 8;

  // shfl source lanes for the P repack (per-thread constants)
  const int gA = (kg & 1) * 32 + fr;   // group (kg&1)*2, same fr
  const int gB = gA + 16;              // group (kg&1)*2+1
  const bool hiSel = (kg >> 1) != 0;   // selects ni = 2*kk + (kg>>1)

  // Q fragments in registers (32 rows/wave)
  bf16x8 aq[2][2];
  for (int sub = 0; sub < 2; ++sub) {
    const bf16* qr = qb + (size_t)(q0 + w * 32 + sub * 16 + fr) * 64 + kg * 8;
    aq[sub][0] = *(const bf16x8*)(qr);
    aq[sub][1] = *(const bf16x8*)(qr + 32);
  }

  float m_run[2] = {-1e30f, -1e30f}, l_run[2] = {0.f, 0.f};
  f32x4 o_acc[2][4] = {};   // O^T: o_acc[sub][d-tile]; col=fr=q, row=kg*4+r=d-local

  const int nt = 2 * qt + 2;

  // prologue: stage tile 0 into buf 0
  for (int t = 0; t < 2; ++t) {
    const int i = w * 2 + t;
    gl_lds16(kb + (size_t)(i * 8) * 64, KsB[0] + i * 512);
    gl_lds16(vb + (size_t)(i * 8) * Ss, VtB[0] + i * 512);
  }

  int cur = 0;
  for (int it = 0; it < nt; ++it) {
    const int kv0 = it * 64;
    __syncthreads();  // drains vmcnt: stage(it) complete; prev-tile reads done
    if (it + 1 < nt) {
      const int kvn = kv0 + 64;
      for (int t = 0; t < 2; ++t) {
        const int i = w * 2 + t;
        gl_lds16(kb + (size_t)(kvn + i * 8) * 64, KsB[cur ^ 1] + i * 512);
        gl_lds16(vb + (size_t)(i * 8) * Ss + kvn, VtB[cur ^ 1] + i * 512);
      }
    }
    const bool active = (kv0 <= q0 + w * 32 + 31);  // wave-uniform
    if (active) {
      // ---- S^T = K Q (swapped operands) ----
      f32x4 sacc[2][4] = {};
      for (int kk = 0; kk < 2; ++kk) {
        bf16x8 bk[4];
        for (int ni = 0; ni < 4; ++ni) {
          const int rb = ni * 16 + fr;
          bk[ni] = *(const bf16x8*)(KsB[cur] + rb * 64 + (((kk * 4 + kg) ^ (rb & 7)) * 8));
        }
        __builtin_amdgcn_s_setprio(1);
        for (int sub = 0; sub < 2; ++sub)
          for (int ni = 0; ni < 4; ++ni)
            sacc[sub][ni] =
                __builtin_amdgcn_mfma_f32_16x16x32_bf16(bk[ni], aq[sub][kk], sacc[sub][ni], 0, 0, 0);
        __builtin_amdgcn_s_setprio(0);
      }
      // ---- softmax, in-lane (lane owns q = qs+fr; k = kv0 + ni*16 + kg*4 + r) ----
      bf16x8 bp[2][2];  // [sub][kk] PV B-operand fragments
      for (int sub = 0; sub < 2; ++sub) {
        const int qs = q0 + w * 32 + sub * 16;
        float p[4][4];
        float mnew = -1e30f;
        if (kv0 + 63 > qs) {
          const int q = qs + fr;
          for (int ni = 0; ni < 4; ++ni)
            for (int r = 0; r < 4; ++r) {
              const int k = kv0 + ni * 16 + kg * 4 + r;
              float s = sacc[sub][ni][r];
              if (k > q) s = -1e30f;
              p[ni][r] = s;
              mnew = fmaxf(mnew, s);
            }
        } else {
          for (int ni = 0; ni < 4; ++ni)
            for (int r = 0; r < 4; ++r) {
              float s = sacc[sub][ni][r];
              p[ni][r] = s;
              mnew = fmaxf(mnew, s);
            }
        }
        mnew = fmaxf(mnew, __shfl_xor(mnew, 16, 64));
        mnew = fmaxf(mnew, __shfl_xor(mnew, 32, 64));
        // defer-max (T13): skip rescale when all rows' max growth <= 8 (log2 units)
        float mn;
        if (__all(mnew - m_run[sub] <= 8.f)) {
          mn = m_run[sub];
        } else {
          mn = fmaxf(m_run[sub], mnew);
          const float fs = exp2f(m_run[sub] - mn);
          m_run[sub] = mn;
          l_run[sub] *= fs;
          for (int ni = 0; ni < 4; ++ni)
            for (int r = 0; r < 4; ++r)
              o_acc[sub][ni][r] *= fs;
        }
        float rs = 0.f;
        for (int ni = 0; ni < 4; ++ni)
          for (int r = 0; r < 4; ++r) {
            const float e = exp2f(p[ni][r] - mn);
            p[ni][r] = e;
            rs += e;
          }
        rs += __shfl_xor(rs, 16, 64);
        rs += __shfl_xor(rs, 32, 64);
        l_run[sub] += rs;
        // pack p -> bf16 word pairs per k-subtile
        unsigned int Wlo[4], Whi[4];
        for (int ni = 0; ni < 4; ++ni) {
          Wlo[ni] = pkbf(p[ni][0], p[ni][1]);
          Whi[ni] = pkbf(p[ni][2], p[ni][3]);
        }
        // exchange: lane (fr,kg) gathers P^T[k=kk*32+kg*8+j][q=fr]
        for (int kk = 0; kk < 2; ++kk) {
          const int i0 = 2 * kk, i1 = 2 * kk + 1;
          unsigned int a0 = (unsigned int)__shfl((int)Wlo[i0], gA, 64);
          unsigned int a1 = (unsigned int)__shfl((int)Wlo[i1], gA, 64);
          unsigned int b0 = (unsigned int)__shfl((int)Whi[i0], gA, 64);
          unsigned int b1 = (unsigned int)__shfl((int)Whi[i1], gA, 64);
          unsigned int c0 = (unsigned int)__shfl((int)Wlo[i0], gB, 64);
          unsigned int c1 = (unsigned int)__shfl((int)Wlo[i1], gB, 64);
          unsigned int d0 = (unsigned int)__shfl((int)Whi[i0], gB, 64);
          unsigned int d1 = (unsigned int)__shfl((int)Whi[i1], gB, 64);
          u32x4 wv = {hiSel ? a1 : a0, hiSel ? b1 : b0, hiSel ? c1 : c0, hiSel ? d1 : d0};
          bp[sub][kk] = __builtin_bit_cast(bf16x8, wv);
        }
      }
      // ---- O^T += V^T P^T ----
      for (int kk = 0; kk < 2; ++kk) {
        bf16x8 bv[4];
        for (int ni = 0; ni < 4; ++ni) {
          const int rb = ni * 16 + fr;
          bv[ni] = *(const bf16x8*)(VtB[cur] + rb * 64 + (((kk * 4 + kg) ^ (rb & 7)) * 8));
        }
        __builtin_amdgcn_s_setprio(1);
        for (int sub = 0; sub < 2; ++sub)
          for (int ni = 0; ni < 4; ++ni)
            o_acc[sub][ni] =
                __builtin_amdgcn_mfma_f32_16x16x32_bf16(bv[ni], bp[sub][kk], o_acc[sub][ni], 0, 0, 0);
        __builtin_amdgcn_s_setprio(0);
      }
    }
    cur ^= 1;
  }

  // epilogue: O^T -> vals[b, q, h*64+d]; lane owns q=qs+fr, d = ni*16+kg*4+{0..3}
  for (int sub = 0; sub < 2; ++sub) {
    const float inv = 1.f / l_run[sub];
    const int q = q0 + w * 32 + sub * 16 + fr;
    bf16* dst = vals + ((size_t)b * Ss + q) * Ee + h * 64 + kg * 4;
    for (int ni = 0; ni < 4; ++ni) {
      u32x2 pk2 = {pkbf(o_acc[sub][ni][0] * inv, o_acc[sub][ni][1] * inv),
                   pkbf(o_acc[sub][ni][2] * inv, o_acc[sub][ni][3] * inv)};
      *(u32x2*)(dst + ni * 16) = pk2;
    }
  }
}

// ---------------- launch ----------------

extern "C" void kernel_launch(void* const* d_in, const int* in_sizes, int n_in,
                              void* d_out, int out_size, void* d_ws, size_t ws_size,
                              hipStream_t stream) {
  const float* x    = (const float*)d_in[0];
  const float* Wqkv = (const float*)d_in[1];
  const float* bqkv = (const float*)d_in[2];
  const float* Wout = (const float*)d_in[3];
  const float* bout = (const float*)d_in[4];
  float* out = (float*)d_out;

  // workspace layout (<= 88 MiB). Skews of 192/384 KiB de-alias L2 sets among the
  // attn inputs (verified r9: attn 119.7 -> 96 us). valsb overlaps dead x_bf.
  char* ws = (char*)d_ws;
  const size_t MiB = 1048576, KiB = 1024;
  bf16* x_bf  = (bf16*)(ws);                            // 16 MiB  [8192,1024] (dead after qkv_gemm)
  bf16* valsb = (bf16*)(ws);                            // 16 MiB  [8192,1024] (written by attn)
  bf16* WqkvT = (bf16*)(ws + 16 * MiB);                 //  6 MiB  [3072,1024]
  bf16* WoutT = (bf16*)(ws + 22 * MiB);                 //  2 MiB  [1024,1024]
  bf16* qbuf  = (bf16*)(ws + 24 * MiB);                 // 16 MiB  [64][2048][64] scaled
  bf16* kbuf  = (bf16*)(ws + 40 * MiB + 192 * KiB);     // 16 MiB  [64][2048][64]
  bf16* vtb   = (bf16*)(ws + 56 * MiB + 384 * KiB);     // 16 MiB  [64][64][2048]

  k_cvt_bf16<<<dim3(Mm * Ee / 2048), dim3(256), 0, stream>>>(x, x_bf, Mm * Ee);
  k_transpose_cvt<<<dim3(N_QKV / 32, Ee / 32), dim3(32, 8), 0, stream>>>(Wqkv, WqkvT, Ee, N_QKV);
  k_transpose_cvt<<<dim3(Ee / 32, Ee / 32), dim3(32, 8), 0, stream>>>(Wout, WoutT, Ee, Ee);
  k_qkv_gemm<<<dim3(N_QKV / 128, Mm / 256), dim3(512), 0, stream>>>(x_bf, WqkvT, bqkv, qbuf, kbuf, vtb);
  k_attn<<<dim3(Ss / 128 * Hh * Bb), dim3(256), 0, stream>>>(qbuf, kbuf, vtb, valsb);
  k_out_gemm<<<dim3(Ee / 128, Mm / 256), dim3(512), 0, stream>>>(valsb, WoutT, bout, out);
}

// Round 13
// 186.666 us; speedup vs baseline: 1.1047x; 1.1047x over previous
//
#include <hip/hip_runtime.h>
#include <hip/hip_bf16.h>
#include <cstdint>
#include <cstddef>

typedef __bf16 bf16;
typedef __bf16 bf16x8 __attribute__((ext_vector_type(8)));
typedef float f32x4 __attribute__((ext_vector_type(4)));
typedef unsigned int u32x4 __attribute__((ext_vector_type(4)));
typedef unsigned int u32x2 __attribute__((ext_vector_type(2)));

#define DEVINL __device__ __forceinline__

namespace {
constexpr int Bb = 4, Ss = 2048, Ee = 1024, Hh = 16;
constexpr int Mm = Bb * Ss;      // 8192 rows
constexpr int N_QKV = 3 * Ee;    // 3072
constexpr float SCQ = 0.03125f * 1.44269504f;  // (1/sqrt(E)) * log2(e), folded into Q
}

DEVINL void gl_lds16(const bf16* g, bf16* l) {
  __builtin_amdgcn_global_load_lds((const __attribute__((address_space(1))) void*)g,
                                   (__attribute__((address_space(3))) void*)l, 16, 0, 0);
}

DEVINL unsigned int pkbf(float a, float b) {
  bf16 x = (bf16)a, y = (bf16)b;
  return (unsigned int)__builtin_bit_cast(unsigned short, x) |
         ((unsigned int)__builtin_bit_cast(unsigned short, y) << 16);
}

// ---------------- fused prep: x->bf16 + both weight transposes, ONE launch ----------------
// grid: [0,4096) cvt x (2048 elems/block); [4096,7168) Wqkv^T 32x32 tiles; [7168,8192) Wout^T.

__global__ __launch_bounds__(256) void k_prep(const float* __restrict__ x, bf16* __restrict__ x_bf,
                                              const float* __restrict__ Wqkv, bf16* __restrict__ WqkvT,
                                              const float* __restrict__ Wout, bf16* __restrict__ WoutT) {
  __shared__ float tile[32][33];
  const int gb = blockIdx.x;
  if (gb < 4096) {
    const int i = (gb * 256 + threadIdx.x) * 8;
    float4 a = *(const float4*)(x + i);
    float4 c = *(const float4*)(x + i + 4);
    bf16x8 v = {(bf16)a.x, (bf16)a.y, (bf16)a.z, (bf16)a.w,
                (bf16)c.x, (bf16)c.y, (bf16)c.z, (bf16)c.w};
    *(bf16x8*)(x_bf + i) = v;
    return;
  }
  // transpose partition: out[c][r] = (bf16) in[r][c], tiles of 32x32, 256 thr as (32,8)
  const float* in;
  bf16* outp;
  int R, C, bx, by;
  if (gb < 4096 + 3072) {
    const int g = gb - 4096;
    in = Wqkv; outp = WqkvT; R = Ee; C = N_QKV;
    bx = g % 96; by = g / 96;        // C/32=96, R/32=32
  } else {
    const int g = gb - 4096 - 3072;
    in = Wout; outp = WoutT; R = Ee; C = Ee;
    bx = g % 32; by = g / 32;        // 32 x 32
  }
  const int c0 = bx * 32, r0 = by * 32;
  const int tx = threadIdx.x & 31, ty = threadIdx.x >> 5;
  for (int i = 0; i < 32; i += 8)
    tile[ty + i][tx] = in[(size_t)(r0 + ty + i) * C + (c0 + tx)];
  __syncthreads();
  for (int i = 0; i < 32; i += 8)
    outp[(size_t)(c0 + ty + i) * R + (r0 + tx)] = (bf16)tile[tx][ty + i];
}

// ---------------- deep-pipelined GEMM core (r10 verbatim: BM=256, BK=64, 512 thr / 8 waves) -------
// 2-buffer, counted vmcnt (leave one tile's loads in flight), stage into freed buffer after
// the second barrier so it flies under the MFMA burst. Measured best (r10: total 191.3).

template <int NF>
DEVINL void gemm_core256(const bf16* __restrict__ A, const bf16* __restrict__ Bt,
                         int m0, int n0, bf16* As, bf16* Bs, f32x4 (&acc)[8][NF]) {
  constexpr int K = 1024;
  constexpr int TILEA = 16384;        // 256*64 elems
  constexpr int TILEB = NF * 4096;    // BN*64 elems
  const int tid = threadIdx.x;
  const int w = tid >> 6, lane = tid & 63;
  const int wm = w >> 2, wn = w & 3;
  const int fr = lane & 15, kg = lane >> 4;
  const int gc = (tid & 7) ^ ((tid >> 3) & 7);  // pre-swizzled global chunk
  const int srow = tid >> 3;                    // staging row within 64-row slab
  const bf16* Ag = A + (size_t)(m0 + srow) * K + gc * 8;
  const bf16* Bg = Bt + (size_t)(n0 + srow) * K + gc * 8;
  bf16* AdW = As + w * 512;  // wave-uniform LDS base (w*8 rows * 64)
  bf16* BdW = Bs + w * 512;

#define STAGE_TILE(kt, buf)                                                       \
  {                                                                               \
    for (int i = 0; i < 4; ++i)                                                   \
      gl_lds16(Ag + (kt) + (size_t)(i * 64) * K, AdW + (buf) * TILEA + i * 4096); \
    for (int i = 0; i < NF; ++i)                                                  \
      gl_lds16(Bg + (kt) + (size_t)(i * 64) * K, BdW + (buf) * TILEB + i * 4096); \
  }

  STAGE_TILE(0, 0)
  STAGE_TILE(64, 1)
  constexpr int nt = K / 64;  // 16
  for (int t = 0; t < nt; ++t) {
    const int cur = t & 1;
    if constexpr (NF == 3) {
      asm volatile("s_waitcnt vmcnt(7)" ::: "memory");
    } else {
      asm volatile("s_waitcnt vmcnt(6)" ::: "memory");
    }
    __builtin_amdgcn_sched_barrier(0);
    __builtin_amdgcn_s_barrier();
    __builtin_amdgcn_sched_barrier(0);
    bf16x8 af[2][8], bfx[2][NF];
    const bf16* Ab = As + cur * TILEA;
    const bf16* Bb = Bs + cur * TILEB;
    for (int kk = 0; kk < 2; ++kk) {
      const int sw = ((kk * 4 + kg) ^ (fr & 7)) * 8;
      for (int mi = 0; mi < 8; ++mi)
        af[kk][mi] = *(const bf16x8*)(Ab + (wm * 128 + mi * 16 + fr) * 64 + sw);
      for (int ni = 0; ni < NF; ++ni)
        bfx[kk][ni] = *(const bf16x8*)(Bb + (wn * (NF * 16) + ni * 16 + fr) * 64 + sw);
    }
    asm volatile("s_waitcnt lgkmcnt(0)" ::: "memory");
    __builtin_amdgcn_sched_barrier(0);
    __builtin_amdgcn_s_barrier();
    __builtin_amdgcn_sched_barrier(0);
    if (t + 2 < nt) STAGE_TILE((t + 2) * 64, cur)  // freed buffer; flies under MFMA
    __builtin_amdgcn_s_setprio(1);
    for (int kk = 0; kk < 2; ++kk)
      for (int mi = 0; mi < 8; ++mi)
        for (int ni = 0; ni < NF; ++ni)
          acc[mi][ni] =
              __builtin_amdgcn_mfma_f32_16x16x32_bf16(af[kk][mi], bfx[kk][ni], acc[mi][ni], 0, 0, 0);
    __builtin_amdgcn_s_setprio(0);
  }
#undef STAGE_TILE
}

// QKV GEMM: BN=192. grid (16, 32) = 512 blocks, 512 threads.
__global__ __launch_bounds__(512, 2) void k_qkv_gemm(const bf16* __restrict__ A,
                                                     const bf16* __restrict__ Bt,
                                                     const float* __restrict__ bias,
                                                     bf16* __restrict__ qbuf,
                                                     bf16* __restrict__ kbuf,
                                                     bf16* __restrict__ vtb) {
  __shared__ bf16 As[2 * 16384];
  __shared__ bf16 Bs[2 * 3 * 4096];
  const int m0 = blockIdx.y * 256, n0 = blockIdx.x * 192;
  f32x4 acc[8][3] = {};
  gemm_core256<3>(A, Bt, m0, n0, As, Bs, acc);

  const int tid = threadIdx.x, w = tid >> 6, lane = tid & 63;
  const int wm = w >> 2, wn = w & 3;
  const int fr = lane & 15, kg = lane >> 4;
  const int row_b = m0 >> 11;  // batch index (256-row tile never straddles a batch)
  for (int ni = 0; ni < 3; ++ni) {
    const int col0 = n0 + wn * 48 + ni * 16;
    const int h = col0 / 192;
    const int w192 = col0 - h * 192;
    const int cls = w192 >> 6;  // 0=Q, 1=K, 2=V (uniform per (wn,ni): 16 | 192)
    const float bv = bias[col0 + fr];
    if (cls == 2) {
      const int d = w192 - 128 + fr;
      bf16* dstb = vtb + (((size_t)row_b * Hh + h) * 64 + d) * Ss;
      for (int mi = 0; mi < 8; ++mi) {
        const int s0 = (m0 & 2047) + wm * 128 + mi * 16 + kg * 4;
        u32x2 pk2 = {pkbf(acc[mi][ni][0] + bv, acc[mi][ni][1] + bv),
                     pkbf(acc[mi][ni][2] + bv, acc[mi][ni][3] + bv)};
        *(u32x2*)(dstb + s0) = pk2;
      }
    } else {
      bf16* buf = (cls == 0) ? qbuf : kbuf;
      const float sc = (cls == 0) ? SCQ : 1.f;
      const int d = (w192 & 63) + fr;
      bf16* dstb = buf + ((size_t)row_b * Hh + h) * Ss * 64 + d;
      for (int mi = 0; mi < 8; ++mi) {
        const int s0 = (m0 & 2047) + wm * 128 + mi * 16 + kg * 4;
        for (int r = 0; r < 4; ++r)
          dstb[(size_t)(s0 + r) * 64] = (bf16)((acc[mi][ni][r] + bv) * sc);
      }
    }
  }
}

// OUT GEMM: BN=128. grid (8, 32) = 256 blocks, 512 threads.
__global__ __launch_bounds__(512, 2) void k_out_gemm(const bf16* __restrict__ A,
                                                     const bf16* __restrict__ Bt,
                                                     const float* __restrict__ bias,
                                                     float* __restrict__ out) {
  __shared__ bf16 As[2 * 16384];
  __shared__ bf16 Bs[2 * 2 * 4096];
  const int m0 = blockIdx.y * 256, n0 = blockIdx.x * 128;
  f32x4 acc[8][2] = {};
  gemm_core256<2>(A, Bt, m0, n0, As, Bs, acc);

  const int tid = threadIdx.x, w = tid >> 6, lane = tid & 63;
  const int wm = w >> 2, wn = w & 3;
  const int fr = lane & 15, kg = lane >> 4;
  for (int ni = 0; ni < 2; ++ni) {
    const int col = n0 + wn * 32 + ni * 16 + fr;
    const float bv = bias[col];
    for (int mi = 0; mi < 8; ++mi) {
      const int mb = m0 + wm * 128 + mi * 16 + kg * 4;
      for (int r = 0; r < 4; ++r)
        out[(size_t)(mb + r) * Ee + col] = acc[mi][ni][r] + bv;
    }
  }
}

// ---------------- flash attention (causal; Q pre-scaled by 1/32*log2e) ----------------
// r9/r10 source (96 us, measured thrice). Swapped-operand in-lane softmax, defer-max, LPT.

__global__ __launch_bounds__(256, 3) void k_attn(const bf16* __restrict__ qbuf,
                                                 const bf16* __restrict__ kbuf,
                                                 const bf16* __restrict__ vtb,
                                                 bf16* __restrict__ vals) {
  const int g = blockIdx.x;
  const int qt = 15 - (g >> 6);   // heavy blocks first (LPT)
  const int bh = g & 63;
  const int b = bh >> 4, h = bh & 15;
  const int q0 = qt * 128;
  const int tid = threadIdx.x, w = tid >> 6, lane = tid & 63;
  const int fr = lane & 15, kg = lane >> 4;
  const int rl = lane >> 3, cl = (lane & 7) ^ (lane >> 3);

  __shared__ bf16 KsB[2][4096];   // [key 64][chunk-swizzled d 64]
  __shared__ bf16 VtB[2][4096];   // [d 64][chunk-swizzled s 64]

  const bf16* qb = qbuf + (size_t)bh * Ss * 64;
  const bf16* kb = kbuf + (size_t)bh * Ss * 64 + (size_t)rl * 64 + cl * 8;
  const bf16* vb = vtb + (size_t)bh * 64 * Ss + (size_t)rl * Ss + cl * 8;

  // shfl source lanes for the P repack (per-thread constants)
  const int gA = (kg & 1) * 32 + fr;   // group (kg&1)*2, same fr
  const int gB = gA + 16;              // group (kg&1)*2+1
  const bool hiSel = (kg >> 1) != 0;   // selects ni = 2*kk + (kg>>1)

  // Q fragments in registers (32 rows/wave)
  bf16x8 aq[2][2];
  for (int sub = 0; sub < 2; ++sub) {
    const bf16* qr = qb + (size_t)(q0 + w * 32 + sub * 16 + fr) * 64 + kg * 8;
    aq[sub][0] = *(const bf16x8*)(qr);
    aq[sub][1] = *(const bf16x8*)(qr + 32);
  }

  float m_run[2] = {-1e30f, -1e30f}, l_run[2] = {0.f, 0.f};
  f32x4 o_acc[2][4] = {};   // O^T: o_acc[sub][d-tile]; col=fr=q, row=kg*4+r=d-local

  const int nt = 2 * qt + 2;

  // prologue: stage tile 0 into buf 0
  for (int t = 0; t < 2; ++t) {
    const int i = w * 2 + t;
    gl_lds16(kb + (size_t)(i * 8) * 64, KsB[0] + i * 512);
    gl_lds16(vb + (size_t)(i * 8) * Ss, VtB[0] + i * 512);
  }

  int cur = 0;
  for (int it = 0; it < nt; ++it) {
    const int kv0 = it * 64;
    __syncthreads();  // drains vmcnt: stage(it) complete; prev-tile reads done
    if (it + 1 < nt) {
      const int kvn = kv0 + 64;
      for (int t = 0; t < 2; ++t) {
        const int i = w * 2 + t;
        gl_lds16(kb + (size_t)(kvn + i * 8) * 64, KsB[cur ^ 1] + i * 512);
        gl_lds16(vb + (size_t)(i * 8) * Ss + kvn, VtB[cur ^ 1] + i * 512);
      }
    }
    const bool active = (kv0 <= q0 + w * 32 + 31);  // wave-uniform
    if (active) {
      // ---- S^T = K Q (swapped operands) ----
      f32x4 sacc[2][4] = {};
      for (int kk = 0; kk < 2; ++kk) {
        bf16x8 bk[4];
        for (int ni = 0; ni < 4; ++ni) {
          const int rb = ni * 16 + fr;
          bk[ni] = *(const bf16x8*)(KsB[cur] + rb * 64 + (((kk * 4 + kg) ^ (rb & 7)) * 8));
        }
        __builtin_amdgcn_s_setprio(1);
        for (int sub = 0; sub < 2; ++sub)
          for (int ni = 0; ni < 4; ++ni)
            sacc[sub][ni] =
                __builtin_amdgcn_mfma_f32_16x16x32_bf16(bk[ni], aq[sub][kk], sacc[sub][ni], 0, 0, 0);
        __builtin_amdgcn_s_setprio(0);
      }
      // ---- softmax, in-lane (lane owns q = qs+fr; k = kv0 + ni*16 + kg*4 + r) ----
      bf16x8 bp[2][2];  // [sub][kk] PV B-operand fragments
      for (int sub = 0; sub < 2; ++sub) {
        const int qs = q0 + w * 32 + sub * 16;
        float p[4][4];
        float mnew = -1e30f;
        if (kv0 + 63 > qs) {
          const int q = qs + fr;
          for (int ni = 0; ni < 4; ++ni)
            for (int r = 0; r < 4; ++r) {
              const int k = kv0 + ni * 16 + kg * 4 + r;
              float s = sacc[sub][ni][r];
              if (k > q) s = -1e30f;
              p[ni][r] = s;
              mnew = fmaxf(mnew, s);
            }
        } else {
          for (int ni = 0; ni < 4; ++ni)
            for (int r = 0; r < 4; ++r) {
              float s = sacc[sub][ni][r];
              p[ni][r] = s;
              mnew = fmaxf(mnew, s);
            }
        }
        mnew = fmaxf(mnew, __shfl_xor(mnew, 16, 64));
        mnew = fmaxf(mnew, __shfl_xor(mnew, 32, 64));
        // defer-max (T13): skip rescale when all rows' max growth <= 8 (log2 units)
        float mn;
        if (__all(mnew - m_run[sub] <= 8.f)) {
          mn = m_run[sub];
        } else {
          mn = fmaxf(m_run[sub], mnew);
          const float fs = exp2f(m_run[sub] - mn);
          m_run[sub] = mn;
          l_run[sub] *= fs;
          for (int ni = 0; ni < 4; ++ni)
            for (int r = 0; r < 4; ++r)
              o_acc[sub][ni][r] *= fs;
        }
        float rs = 0.f;
        for (int ni = 0; ni < 4; ++ni)
          for (int r = 0; r < 4; ++r) {
            const float e = exp2f(p[ni][r] - mn);
            p[ni][r] = e;
            rs += e;
          }
        rs += __shfl_xor(rs, 16, 64);
        rs += __shfl_xor(rs, 32, 64);
        l_run[sub] += rs;
        // pack p -> bf16 word pairs per k-subtile
        unsigned int Wlo[4], Whi[4];
        for (int ni = 0; ni < 4; ++ni) {
          Wlo[ni] = pkbf(p[ni][0], p[ni][1]);
          Whi[ni] = pkbf(p[ni][2], p[ni][3]);
        }
        // exchange: lane (fr,kg) gathers P^T[k=kk*32+kg*8+j][q=fr]
        for (int kk = 0; kk < 2; ++kk) {
          const int i0 = 2 * kk, i1 = 2 * kk + 1;
          unsigned int a0 = (unsigned int)__shfl((int)Wlo[i0], gA, 64);
          unsigned int a1 = (unsigned int)__shfl((int)Wlo[i1], gA, 64);
          unsigned int b0 = (unsigned int)__shfl((int)Whi[i0], gA, 64);
          unsigned int b1 = (unsigned int)__shfl((int)Whi[i1], gA, 64);
          unsigned int c0 = (unsigned int)__shfl((int)Wlo[i0], gB, 64);
          unsigned int c1 = (unsigned int)__shfl((int)Wlo[i1], gB, 64);
          unsigned int d0 = (unsigned int)__shfl((int)Whi[i0], gB, 64);
          unsigned int d1 = (unsigned int)__shfl((int)Whi[i1], gB, 64);
          u32x4 wv = {hiSel ? a1 : a0, hiSel ? b1 : b0, hiSel ? c1 : c0, hiSel ? d1 : d0};
          bp[sub][kk] = __builtin_bit_cast(bf16x8, wv);
        }
      }
      // ---- O^T += V^T P^T ----
      for (int kk = 0; kk < 2; ++kk) {
        bf16x8 bv[4];
        for (int ni = 0; ni < 4; ++ni) {
          const int rb = ni * 16 + fr;
          bv[ni] = *(const bf16x8*)(VtB[cur] + rb * 64 + (((kk * 4 + kg) ^ (rb & 7)) * 8));
        }
        __builtin_amdgcn_s_setprio(1);
        for (int sub = 0; sub < 2; ++sub)
          for (int ni = 0; ni < 4; ++ni)
            o_acc[sub][ni] =
                __builtin_amdgcn_mfma_f32_16x16x32_bf16(bv[ni], bp[sub][kk], o_acc[sub][ni], 0, 0, 0);
        __builtin_amdgcn_s_setprio(0);
      }
    }
    cur ^= 1;
  }

  // epilogue: O^T -> vals[b, q, h*64+d]; lane owns q=qs+fr, d = ni*16+kg*4+{0..3}
  for (int sub = 0; sub < 2; ++sub) {
    const float inv = 1.f / l_run[sub];
    const int q = q0 + w * 32 + sub * 16 + fr;
    bf16* dst = vals + ((size_t)b * Ss + q) * Ee + h * 64 + kg * 4;
    for (int ni = 0; ni < 4; ++ni) {
      u32x2 pk2 = {pkbf(o_acc[sub][ni][0] * inv, o_acc[sub][ni][1] * inv),
                   pkbf(o_acc[sub][ni][2] * inv, o_acc[sub][ni][3] * inv)};
      *(u32x2*)(dst + ni * 16) = pk2;
    }
  }
}

// ---------------- launch ----------------

extern "C" void kernel_launch(void* const* d_in, const int* in_sizes, int n_in,
                              void* d_out, int out_size, void* d_ws, size_t ws_size,
                              hipStream_t stream) {
  const float* x    = (const float*)d_in[0];
  const float* Wqkv = (const float*)d_in[1];
  const float* bqkv = (const float*)d_in[2];
  const float* Wout = (const float*)d_in[3];
  const float* bout = (const float*)d_in[4];
  float* out = (float*)d_out;

  // workspace layout (<= 88 MiB). Skews of 192/384 KiB de-alias L2 sets among the
  // attn inputs (verified r9: attn 119.7 -> 96 us). valsb overlaps dead x_bf.
  char* ws = (char*)d_ws;
  const size_t MiB = 1048576, KiB = 1024;
  bf16* x_bf  = (bf16*)(ws);                            // 16 MiB  [8192,1024] (dead after qkv_gemm)
  bf16* valsb = (bf16*)(ws);                            // 16 MiB  [8192,1024] (written by attn)
  bf16* WqkvT = (bf16*)(ws + 16 * MiB);                 //  6 MiB  [3072,1024]
  bf16* WoutT = (bf16*)(ws + 22 * MiB);                 //  2 MiB  [1024,1024]
  bf16* qbuf  = (bf16*)(ws + 24 * MiB);                 // 16 MiB  [64][2048][64] scaled
  bf16* kbuf  = (bf16*)(ws + 40 * MiB + 192 * KiB);     // 16 MiB  [64][2048][64]
  bf16* vtb   = (bf16*)(ws + 56 * MiB + 384 * KiB);     // 16 MiB  [64][64][2048]

  k_prep<<<dim3(4096 + 3072 + 1024), dim3(256), 0, stream>>>(x, x_bf, Wqkv, WqkvT, Wout, WoutT);
  k_qkv_gemm<<<dim3(N_QKV / 192, Mm / 256), dim3(512), 0, stream>>>(x_bf, WqkvT, bqkv, qbuf, kbuf, vtb);
  k_attn<<<dim3(Ss / 128 * Hh * Bb), dim3(256), 0, stream>>>(qbuf, kbuf, vtb, valsb);
  k_out_gemm<<<dim3(Ee / 128, Mm / 256), dim3(512), 0, stream>>>(valsb, WoutT, bout, out);
}